// Round 3
// baseline (618.855 us; speedup 1.0000x reference)
//
#include <hip/hip_runtime.h>

#define B_ 4
#define N_ 2048
#define D_ 2048

#define BM 128
#define BN 128
#define BK 32

typedef __bf16 bf16x8 __attribute__((ext_vector_type(8)));
typedef float  f32x4  __attribute__((ext_vector_type(4)));

__device__ __forceinline__ ushort f2bf(float x) {
  union { float f; unsigned u; } c; c.f = x;
  unsigned u = c.u;
  u += 0x7fffu + ((u >> 16) & 1u);   // RNE
  return (ushort)(u >> 16);
}

// async global->LDS, 16B per lane; lds base must be wave-uniform (HW adds lane*16)
__device__ __forceinline__ void gld16(ushort* lds, const ushort* g) {
  __builtin_amdgcn_global_load_lds(
      (const __attribute__((address_space(1))) void*)g,
      (__attribute__((address_space(3))) void*)lds, 16, 0, 0);
}

// ---------------- prep kernels ----------------

// one block per row: cn = bf16(data * rsqrt(max(sum(data^2),eps))), catA[:, :D] = bf16(data)
__global__ void prep_cn(const float* __restrict__ data, ushort* __restrict__ cn,
                        ushort* __restrict__ catA) {
  const int row = blockIdx.x;                 // 0..B*N-1
  const long base = (long)row * D_;
  const float4* r4 = (const float4*)(data + base);
  const int tid = threadIdx.x;                // 256 threads, 8 floats each
  float4 u0 = r4[tid * 2], u1 = r4[tid * 2 + 1];
  float s = u0.x*u0.x + u0.y*u0.y + u0.z*u0.z + u0.w*u0.w
          + u1.x*u1.x + u1.y*u1.y + u1.z*u1.z + u1.w*u1.w;
  #pragma unroll
  for (int o = 32; o > 0; o >>= 1) s += __shfl_down(s, o);
  __shared__ float wsum[4];
  if ((tid & 63) == 0) wsum[tid >> 6] = s;
  __syncthreads();
  const float tot = wsum[0] + wsum[1] + wsum[2] + wsum[3];
  const float sc = rsqrtf(fmaxf(tot, 1e-12f));
  uint4 pc, pd;
  pc.x = (unsigned)f2bf(u0.x * sc) | ((unsigned)f2bf(u0.y * sc) << 16);
  pc.y = (unsigned)f2bf(u0.z * sc) | ((unsigned)f2bf(u0.w * sc) << 16);
  pc.z = (unsigned)f2bf(u1.x * sc) | ((unsigned)f2bf(u1.y * sc) << 16);
  pc.w = (unsigned)f2bf(u1.z * sc) | ((unsigned)f2bf(u1.w * sc) << 16);
  pd.x = (unsigned)f2bf(u0.x) | ((unsigned)f2bf(u0.y) << 16);
  pd.y = (unsigned)f2bf(u0.z) | ((unsigned)f2bf(u0.w) << 16);
  pd.z = (unsigned)f2bf(u1.x) | ((unsigned)f2bf(u1.y) << 16);
  pd.w = (unsigned)f2bf(u1.z) | ((unsigned)f2bf(u1.w) << 16);
  *(uint4*)(cn + base + tid * 8) = pc;
  *(uint4*)(catA + (long)row * (2 * D_) + tid * 8) = pd;
}

// sinusoidal posenc [N][D] in bf16
__global__ void prep_pe(ushort* __restrict__ pe) {
  const int id = blockIdx.x * 256 + threadIdx.x;
  const int n = id >> 11, d = id & (D_ - 1);
  const double e = (double)(2 * (d >> 1)) / (double)D_;
  const double rate = exp(e * -9.210340371976184);   // 10000^-e
  const double ang = (double)n * rate;
  const float v = (d & 1) ? (float)cos(ang) : (float)sin(ang);
  pe[id] = f2bf(v);
}

// out[c][r] = bf16(in[r][c]); in is [R][C] fp32
__global__ void transpose_bf16(const float* __restrict__ in, ushort* __restrict__ out,
                               int R, int C) {
  __shared__ float t[32][33];
  const int c0 = blockIdx.x * 32, r0 = blockIdx.y * 32;
  const int tx = threadIdx.x, ty = threadIdx.y;   // (32,8)
  #pragma unroll
  for (int i = 0; i < 32; i += 8) t[ty + i][tx] = in[(long)(r0 + ty + i) * C + c0 + tx];
  __syncthreads();
  #pragma unroll
  for (int i = 0; i < 32; i += 8) out[(long)(c0 + ty + i) * R + r0 + tx] = f2bf(t[tx][ty + i]);
}

// ---------------- NT GEMM: C[m][n] = sum_k A[m][k]*B[n][k] ----------------
// Double-buffered LDS, ONE barrier per K-iter: prefetch for iter k+1 is issued
// right after the barrier that published iter k's tiles, so the compiler's
// vmcnt(0) drain at the NEXT barrier lands after MFMA+ds_read (~174 cyc) of
// overlap instead of stalling cold. LDS k-chunk XOR swizzle (slot = c ^
// ((r>>1)&3)) keeps ds_read_b128 conflict-free with lane-contiguous staging.
// MODE 0: sim = relu(acc) -> bf16, atomicAdd row sums into csum
// MODE 1: bf16 store
// MODE 2: softplus(acc + csum[row]*w0[col] + bexp[col]) -> bf16 at col+colOff
// MODE 3: fp32 store
template <int MODE>
__global__ __launch_bounds__(256, 2) void gemm_bt(
    const ushort* __restrict__ Ag, const ushort* __restrict__ Bg, void* __restrict__ Cg,
    int K, long sA, long sB, long sC, int ldc, int colOff,
    float* __restrict__ csum, const float* __restrict__ w0, const float* __restrict__ bexp) {
  __shared__ ushort sAt[2][BM * BK];   // [buf][row][k-swizzled], 64B rows
  __shared__ ushort sBt[2][BN * BK];

  const int bz = blockIdx.z;
  const ushort* A  = Ag + (long)bz * sA;
  const ushort* Bp = Bg + (long)bz * sB;

  const int tid = threadIdx.x;
  const int w = tid >> 6, L = tid & 63;
  const int blockRow = blockIdx.x * BM;
  const int blockCol = blockIdx.y * BN;

  // staging: lane L of wave w covers row w*16+L/4 (+64 for round 1),
  // global k-chunk ((L&3) ^ ((L>>3)&3)) so LDS slot order is the swizzled layout
  const int ldRow = w * 16 + (L >> 2);
  const int ldK = (((L & 3) ^ ((L >> 3) & 3)) * 8);
  const ushort* a0 = A  + (long)(blockRow + ldRow) * K + ldK;
  const ushort* a1 = a0 + (long)64 * K;
  const ushort* b0 = Bp + (long)(blockCol + ldRow) * K + ldK;
  const ushort* b1 = b0 + (long)64 * K;

  const int wm = (w & 1) * 64, wn = (w >> 1) * 64;   // wave's 64x64 quadrant
  const int fr = L & 15;                             // fragment row
  const int sw = (((L >> 4) ^ ((fr >> 1) & 3)) * 8); // swizzled k-slot for this lane

  f32x4 acc[4][4] = {};

  const int ws512 = w * 512;

  auto stage = [&](int buf) {
    gld16(&sAt[buf][ws512], a0);        gld16(&sAt[buf][2048 + ws512], a1);
    gld16(&sBt[buf][ws512], b0);        gld16(&sBt[buf][2048 + ws512], b1);
    a0 += BK; a1 += BK; b0 += BK; b1 += BK;
  };
  auto compute = [&](int buf) {
    bf16x8 af[4], bfv[4];
    #pragma unroll
    for (int i = 0; i < 4; i++) af[i]  = *(const bf16x8*)&sAt[buf][(wm + i * 16 + fr) * BK + sw];
    #pragma unroll
    for (int j = 0; j < 4; j++) bfv[j] = *(const bf16x8*)&sBt[buf][(wn + j * 16 + fr) * BK + sw];
    #pragma unroll
    for (int i = 0; i < 4; i++)
      #pragma unroll
      for (int j = 0; j < 4; j++)
        acc[i][j] = __builtin_amdgcn_mfma_f32_16x16x32_bf16(af[i], bfv[j], acc[i][j], 0, 0, 0);
  };

  const int iters = K / BK;   // 64 or 128 — always even
  stage(0);
  __syncthreads();            // buf0 published (vmcnt drained by compiler)
  for (int it = 0; it < iters; it += 2) {
    stage(1);                 // prefetch k+1 — in flight during compute(0)
    compute(0);
    __syncthreads();          // drains prefetch; all waves done reading buf0
    if (it + 2 < iters) stage(0);   // prefetch k+2
    compute(1);
    __syncthreads();
  }

  const int rq = (L >> 4) * 4;   // C/D: row = rq + reg, col = L&15 (m89-verified)
  const int cq = L & 15;

  if (MODE == 0) {
    ushort* C = (ushort*)Cg + (long)bz * sC;
    float rs[4][4];
    #pragma unroll
    for (int i = 0; i < 4; i++)
      #pragma unroll
      for (int r = 0; r < 4; r++) rs[i][r] = 0.f;
    #pragma unroll
    for (int i = 0; i < 4; i++)
      #pragma unroll
      for (int j = 0; j < 4; j++)
        #pragma unroll
        for (int r = 0; r < 4; r++) {
          const float v = fmaxf(acc[i][j][r], 0.f);
          const int row = blockRow + wm + i * 16 + rq + r;
          const int col = blockCol + wn + j * 16 + cq;
          C[(long)row * ldc + col] = f2bf(v);
          rs[i][r] += v;
        }
    #pragma unroll
    for (int i = 0; i < 4; i++)
      #pragma unroll
      for (int r = 0; r < 4; r++) {
        float s = rs[i][r];
        s += __shfl_xor(s, 1); s += __shfl_xor(s, 2);
        s += __shfl_xor(s, 4); s += __shfl_xor(s, 8);
        if (cq == 0) {
          const int row = blockRow + wm + i * 16 + rq + r;
          atomicAdd(&csum[(long)bz * N_ + row], s);
        }
      }
  } else if (MODE == 1) {
    ushort* C = (ushort*)Cg + (long)bz * sC;
    #pragma unroll
    for (int i = 0; i < 4; i++)
      #pragma unroll
      for (int j = 0; j < 4; j++)
        #pragma unroll
        for (int r = 0; r < 4; r++) {
          const int row = blockRow + wm + i * 16 + rq + r;
          const int col = blockCol + wn + j * 16 + cq;
          C[(long)row * ldc + col] = f2bf(acc[i][j][r]);
        }
  } else if (MODE == 2) {
    ushort* C = (ushort*)Cg + (long)bz * sC;
    #pragma unroll
    for (int i = 0; i < 4; i++)
      #pragma unroll
      for (int j = 0; j < 4; j++)
        #pragma unroll
        for (int r = 0; r < 4; r++) {
          const int row = blockRow + wm + i * 16 + rq + r;
          const int col = blockCol + wn + j * 16 + cq;
          const float x = acc[i][j][r] + csum[(long)bz * N_ + row] * w0[col] + bexp[col];
          const float sp = fmaxf(x, 0.f) + log1pf(expf(-fabsf(x)));
          C[(long)row * ldc + colOff + col] = f2bf(sp);
        }
  } else {
    float* C = (float*)Cg + (long)bz * sC;
    #pragma unroll
    for (int i = 0; i < 4; i++)
      #pragma unroll
      for (int j = 0; j < 4; j++)
        #pragma unroll
        for (int r = 0; r < 4; r++) {
          const int row = blockRow + wm + i * 16 + rq + r;
          const int col = blockCol + wn + j * 16 + cq;
          C[(long)row * ldc + col] = acc[i][j][r];
        }
  }
}

// ---------------- launch ----------------
extern "C" void kernel_launch(void* const* d_in, const int* in_sizes, int n_in,
                              void* d_out, int out_size, void* d_ws, size_t ws_size,
                              hipStream_t stream) {
  const float* data    = (const float*)d_in[0];
  const float* W_exp   = (const float*)d_in[1];
  const float* b_exp   = (const float*)d_in[2];
  const float* W_merge = (const float*)d_in[3];

  char* ws = (char*)d_ws;
  const size_t MB = 1024 * 1024;
  ushort* cnv  = (ushort*)(ws);             // 32MB: cn, then reused as v_out
  ushort* sim  = (ushort*)(ws + 32 * MB);   // 32MB
  ushort* pe   = (ushort*)(ws + 64 * MB);   // 8MB
  ushort* weT  = (ushort*)(ws + 72 * MB);   // 8MB:  W_exp[1:,:]^T
  ushort* wmT  = (ushort*)(ws + 80 * MB);   // 16MB: W_merge^T
  ushort* catA = (ushort*)(ws + 96 * MB);   // 64MB: [data | counter] bf16
  float*  csum = (float*)(ws + 160 * MB);   // 128KB

  hipMemsetAsync(csum, 0, (size_t)B_ * N_ * sizeof(float), stream);
  prep_cn<<<B_ * N_, 256, 0, stream>>>(data, cnv, catA);
  prep_pe<<<(N_ * N_) / 256, 256, 0, stream>>>(pe);
  transpose_bf16<<<dim3(D_ / 32, D_ / 32), dim3(32, 8), 0, stream>>>(W_exp + D_, weT, D_, D_);
  transpose_bf16<<<dim3(D_ / 32, (2 * D_) / 32), dim3(32, 8), 0, stream>>>(W_merge, wmT, 2 * D_, D_);

  dim3 g(N_ / BM, N_ / BN, B_), blk(256);
  // G1: sim = relu(cn cn^T), csum row sums
  gemm_bt<0><<<g, blk, 0, stream>>>(cnv, cnv, sim, D_, (long)N_ * D_, (long)N_ * D_,
                                    (long)N_ * N_, N_, 0, csum, nullptr, nullptr);
  // G2: v_out = pe @ sim  (sim symmetric -> NT form), into cnv region (cn is dead)
  gemm_bt<1><<<g, blk, 0, stream>>>(pe, sim, cnv, N_, 0, (long)N_ * N_,
                                    (long)N_ * N_, N_, 0, nullptr, nullptr, nullptr);
  // G3: catA[:, D:] = softplus(v_out @ W_exp[1:] + csum*w0 + b_exp)
  gemm_bt<2><<<g, blk, 0, stream>>>(cnv, weT, catA, N_, (long)N_ * N_, 0,
                                    (long)N_ * 2 * D_, 2 * D_, D_, csum, W_exp, b_exp);
  // G4: out = catA @ W_merge
  gemm_bt<3><<<g, blk, 0, stream>>>(catA, wmT, d_out, 2 * D_, (long)N_ * 2 * D_, 0,
                                    (long)N_ * D_, D_, 0, nullptr, nullptr, nullptr);
}

// Round 6
// 557.083 us; speedup vs baseline: 1.1109x; 1.1109x over previous
//
#include <hip/hip_runtime.h>

#define B_ 4
#define N_ 2048
#define D_ 2048

#define BM 128
#define BN 128
#define BK 32
#define TP 136   // mirror-tile pitch (ushorts): 272B rows -> every row 16B-aligned

typedef __bf16 bf16x8 __attribute__((ext_vector_type(8)));
typedef float  f32x4  __attribute__((ext_vector_type(4)));

__device__ __forceinline__ ushort f2bf(float x) {
  union { float f; unsigned u; } c; c.f = x;
  unsigned u = c.u;
  u += 0x7fffu + ((u >> 16) & 1u);   // RNE
  return (ushort)(u >> 16);
}

// async global->LDS, 16B per lane; lds base must be wave-uniform (HW adds lane*16)
__device__ __forceinline__ void gld16(ushort* lds, const ushort* g) {
  __builtin_amdgcn_global_load_lds(
      (const __attribute__((address_space(1))) void*)g,
      (__attribute__((address_space(3))) void*)lds, 16, 0, 0);
}

// ---------------- prep kernels ----------------

// one block per row: cn = bf16(data * rsqrt(max(sum(data^2),eps))), catA[:, :D] = bf16(data)
__global__ void prep_cn(const float* __restrict__ data, ushort* __restrict__ cn,
                        ushort* __restrict__ catA) {
  const int row = blockIdx.x;                 // 0..B*N-1
  const long base = (long)row * D_;
  const float4* r4 = (const float4*)(data + base);
  const int tid = threadIdx.x;                // 256 threads, 8 floats each
  float4 u0 = r4[tid * 2], u1 = r4[tid * 2 + 1];
  float s = u0.x*u0.x + u0.y*u0.y + u0.z*u0.z + u0.w*u0.w
          + u1.x*u1.x + u1.y*u1.y + u1.z*u1.z + u1.w*u1.w;
  #pragma unroll
  for (int o = 32; o > 0; o >>= 1) s += __shfl_down(s, o);
  __shared__ float wsum[4];
  if ((tid & 63) == 0) wsum[tid >> 6] = s;
  __syncthreads();
  const float tot = wsum[0] + wsum[1] + wsum[2] + wsum[3];
  const float sc = rsqrtf(fmaxf(tot, 1e-12f));
  uint4 pc, pd;
  pc.x = (unsigned)f2bf(u0.x * sc) | ((unsigned)f2bf(u0.y * sc) << 16);
  pc.y = (unsigned)f2bf(u0.z * sc) | ((unsigned)f2bf(u0.w * sc) << 16);
  pc.z = (unsigned)f2bf(u1.x * sc) | ((unsigned)f2bf(u1.y * sc) << 16);
  pc.w = (unsigned)f2bf(u1.z * sc) | ((unsigned)f2bf(u1.w * sc) << 16);
  pd.x = (unsigned)f2bf(u0.x) | ((unsigned)f2bf(u0.y) << 16);
  pd.y = (unsigned)f2bf(u0.z) | ((unsigned)f2bf(u0.w) << 16);
  pd.z = (unsigned)f2bf(u1.x) | ((unsigned)f2bf(u1.y) << 16);
  pd.w = (unsigned)f2bf(u1.z) | ((unsigned)f2bf(u1.w) << 16);
  *(uint4*)(cn + base + tid * 8) = pc;
  *(uint4*)(catA + (long)row * (2 * D_) + tid * 8) = pd;
}

// sinusoidal posenc [N][D] in bf16 — float math (bf16 target tolerates it)
__global__ void prep_pe(ushort* __restrict__ pe) {
  const int id = blockIdx.x * 256 + threadIdx.x;
  const int n = id >> 11, d = id & (D_ - 1);
  const float e = (float)(2 * (d >> 1)) * (1.0f / (float)D_);
  const float rate = expf(e * -9.210340371976184f);   // 10000^-e
  const float ang = (float)n * rate;
  const float v = (d & 1) ? cosf(ang) : sinf(ang);
  pe[id] = f2bf(v);
}

// out[c][r] = bf16(in[r][c]); in is [R][C] fp32
__global__ void transpose_bf16(const float* __restrict__ in, ushort* __restrict__ out,
                               int R, int C) {
  __shared__ float t[32][33];
  const int c0 = blockIdx.x * 32, r0 = blockIdx.y * 32;
  const int tx = threadIdx.x, ty = threadIdx.y;   // (32,8)
  #pragma unroll
  for (int i = 0; i < 32; i += 8) t[ty + i][tx] = in[(long)(r0 + ty + i) * C + c0 + tx];
  __syncthreads();
  #pragma unroll
  for (int i = 0; i < 32; i += 8) out[(long)(c0 + ty + i) * R + r0 + tx] = f2bf(t[tx][ty + i]);
}

// ---------------- G1: symmetric sim = relu(cn cn^T), triangular grid ----------------
// One block per (bi<=bj) tile pair; off-diag writes mirrored tile via LDS transpose.
// csum rows get row-sums (bi range) + col-sums (bj range).
__global__ __launch_bounds__(256, 2) void gemm_sym(
    const ushort* __restrict__ Ag, ushort* __restrict__ Cg, float* __restrict__ csum) {
  __shared__ ushort sAt[BM * BK];
  __shared__ ushort sBt[BN * BK];
  __shared__ ushort tile[128 * TP];   // transposed stash, 16B-aligned rows

  const int bz = blockIdx.z;
  const int t = blockIdx.x;
  int bj = (int)((sqrtf(8.f * (float)t + 1.f) - 1.f) * 0.5f);
  while ((bj + 1) * (bj + 2) / 2 <= t) bj++;
  while (bj * (bj + 1) / 2 > t) bj--;
  const int bi = t - bj * (bj + 1) / 2;

  const ushort* A = Ag + (long)bz * N_ * D_;
  const int blockRow = bi * BM;
  const int blockCol = bj * BN;

  const int tid = threadIdx.x;
  const int w = tid >> 6, L = tid & 63;
  const int ldRow = w * 16 + (L >> 2);
  const int ldK = (((L & 3) ^ ((L >> 3) & 3)) * 8);
  const ushort* a0 = A + (long)(blockRow + ldRow) * D_ + ldK;
  const ushort* a1 = a0 + (long)64 * D_;
  const ushort* b0 = A + (long)(blockCol + ldRow) * D_ + ldK;
  const ushort* b1 = b0 + (long)64 * D_;
  ushort* sA0 = sAt + w * 512;
  ushort* sA1 = sAt + 2048 + w * 512;
  ushort* sB0 = sBt + w * 512;
  ushort* sB1 = sBt + 2048 + w * 512;

  const int wm = (w & 1) * 64, wn = (w >> 1) * 64;
  const int fr = L & 15;
  const int sw = (((L >> 4) ^ ((fr >> 1) & 3)) * 8);

  f32x4 acc[4][4] = {};
  for (int k0 = 0; k0 < D_; k0 += BK) {
    gld16(sA0, a0); gld16(sA1, a1);
    gld16(sB0, b0); gld16(sB1, b1);
    a0 += BK; a1 += BK; b0 += BK; b1 += BK;
    __syncthreads();
    bf16x8 af[4], bfv[4];
    #pragma unroll
    for (int i = 0; i < 4; i++) af[i]  = *(const bf16x8*)&sAt[(wm + i * 16 + fr) * BK + sw];
    #pragma unroll
    for (int j = 0; j < 4; j++) bfv[j] = *(const bf16x8*)&sBt[(wn + j * 16 + fr) * BK + sw];
    #pragma unroll
    for (int i = 0; i < 4; i++)
      #pragma unroll
      for (int j = 0; j < 4; j++)
        acc[i][j] = __builtin_amdgcn_mfma_f32_16x16x32_bf16(af[i], bfv[j], acc[i][j], 0, 0, 0);
    __syncthreads();
  }

  const int rq = (L >> 4) * 4;   // C/D: row = rq + reg, col = L&15
  const int cq = L & 15;
  ushort* C = Cg + (long)bz * N_ * N_;

  float rs[4][4];
  float cs[4];
  #pragma unroll
  for (int i = 0; i < 4; i++)
    #pragma unroll
    for (int r = 0; r < 4; r++) rs[i][r] = 0.f;
  #pragma unroll
  for (int j = 0; j < 4; j++) cs[j] = 0.f;

  const bool offdiag = (bi != bj);
  #pragma unroll
  for (int i = 0; i < 4; i++)
    #pragma unroll
    for (int j = 0; j < 4; j++)
      #pragma unroll
      for (int r = 0; r < 4; r++) {
        const float v = fmaxf(acc[i][j][r], 0.f);
        const int lrow = wm + i * 16 + rq + r;
        const int lcol = wn + j * 16 + cq;
        const ushort bv = f2bf(v);
        C[(long)(blockRow + lrow) * N_ + blockCol + lcol] = bv;
        rs[i][r] += v;
        cs[j] += v;
        if (offdiag) tile[lcol * TP + lrow] = bv;   // transposed stash (scalar stores)
      }

  // row sums -> csum[bi range]
  #pragma unroll
  for (int i = 0; i < 4; i++)
    #pragma unroll
    for (int r = 0; r < 4; r++) {
      float s = rs[i][r];
      s += __shfl_xor(s, 1); s += __shfl_xor(s, 2);
      s += __shfl_xor(s, 4); s += __shfl_xor(s, 8);
      if (cq == 0)
        atomicAdd(&csum[(long)bz * N_ + blockRow + wm + i * 16 + rq + r], s);
    }

  if (offdiag) {
    // col sums (== row sums of mirrored tile) -> csum[bj range]
    #pragma unroll
    for (int j = 0; j < 4; j++) {
      float s = cs[j];                     // this lane: 16 rows of its quadrant-range, col cq
      s += __shfl_xor(s, 16); s += __shfl_xor(s, 32);   // all 64 rows of wave's range
      if (L < 16)
        atomicAdd(&csum[(long)bz * N_ + blockCol + wn + j * 16 + cq], s);
    }
    __syncthreads();   // tile stash complete
    // mirrored tile: row rp of C^T block, halves h; 8 x uint4 (16B) per (rp,h).
    // LDS src: rp*TP(272B) + h*64(128B) + q*8(16B) -> 16B-aligned. Global dst:
    // row base 4096B + h*128B + q*16B -> 16B-aligned, coalesced.
    const int rp = tid >> 1, h = tid & 1;
    const ushort* src = &tile[rp * TP + h * 64];
    ushort* dst = &C[(long)(blockCol + rp) * N_ + blockRow + h * 64];
    #pragma unroll
    for (int q = 0; q < 8; q++)
      *(uint4*)(dst + q * 8) = *(const uint4*)(src + q * 8);
  }
}

// ---------------- NT GEMM: C[m][n] = sum_k A[m][k]*B[n][k] (single-buffer m97) ----------
// Grid is always (16,16,4). Block-index swizzle pins batch z + a y-half to one XCD
// (round-robin lin%8 assumption): B-operand working set per XCD drops to ~4MB -> L2-hot.
// MODE 1: bf16 store
// MODE 2: softplus(acc + csum[row]*w0[col] + bexp[col]) -> bf16 at col+colOff
// MODE 3: fp32 store
template <int MODE>
__global__ __launch_bounds__(256, 2) void gemm_bt(
    const ushort* __restrict__ Ag, const ushort* __restrict__ Bg, void* __restrict__ Cg,
    int K, long sA, long sB, long sC, int ldc, int colOff,
    const float* __restrict__ csum, const float* __restrict__ w0,
    const float* __restrict__ bexp) {
  __shared__ ushort sAt[BM * BK];
  __shared__ ushort sBt[BN * BK];

  // swizzle: lin%8 = "XCD"; each XCD owns (z = xcd>>1, y-half = xcd&1)
  const int lin = blockIdx.x + (blockIdx.y << 4) + (blockIdx.z << 8);
  const int xcd = lin & 7, m = lin >> 3;
  const int bz = xcd >> 1;
  const int by = ((xcd & 1) << 3) + (m >> 4);
  const int bx = m & 15;

  const ushort* A  = Ag + (long)bz * sA;
  const ushort* Bp = Bg + (long)bz * sB;

  const int tid = threadIdx.x;
  const int w = tid >> 6, L = tid & 63;
  const int blockRow = bx * BM;
  const int blockCol = by * BN;

  const int ldRow = w * 16 + (L >> 2);
  const int ldK = (((L & 3) ^ ((L >> 3) & 3)) * 8);
  const ushort* a0 = A  + (long)(blockRow + ldRow) * K + ldK;
  const ushort* a1 = a0 + (long)64 * K;
  const ushort* b0 = Bp + (long)(blockCol + ldRow) * K + ldK;
  const ushort* b1 = b0 + (long)64 * K;
  ushort* sA0 = sAt + w * 512;
  ushort* sA1 = sAt + 2048 + w * 512;
  ushort* sB0 = sBt + w * 512;
  ushort* sB1 = sBt + 2048 + w * 512;

  const int wm = (w & 1) * 64, wn = (w >> 1) * 64;
  const int fr = L & 15;
  const int sw = (((L >> 4) ^ ((fr >> 1) & 3)) * 8);

  f32x4 acc[4][4] = {};
  for (int k0 = 0; k0 < K; k0 += BK) {
    gld16(sA0, a0); gld16(sA1, a1);
    gld16(sB0, b0); gld16(sB1, b1);
    a0 += BK; a1 += BK; b0 += BK; b1 += BK;
    __syncthreads();
    bf16x8 af[4], bfv[4];
    #pragma unroll
    for (int i = 0; i < 4; i++) af[i]  = *(const bf16x8*)&sAt[(wm + i * 16 + fr) * BK + sw];
    #pragma unroll
    for (int j = 0; j < 4; j++) bfv[j] = *(const bf16x8*)&sBt[(wn + j * 16 + fr) * BK + sw];
    #pragma unroll
    for (int i = 0; i < 4; i++)
      #pragma unroll
      for (int j = 0; j < 4; j++)
        acc[i][j] = __builtin_amdgcn_mfma_f32_16x16x32_bf16(af[i], bfv[j], acc[i][j], 0, 0, 0);
    __syncthreads();
  }

  const int rq = (L >> 4) * 4;
  const int cq = L & 15;

  if (MODE == 1) {
    ushort* C = (ushort*)Cg + (long)bz * sC;
    #pragma unroll
    for (int i = 0; i < 4; i++)
      #pragma unroll
      for (int j = 0; j < 4; j++)
        #pragma unroll
        for (int r = 0; r < 4; r++) {
          const int row = blockRow + wm + i * 16 + rq + r;
          const int col = blockCol + wn + j * 16 + cq;
          C[(long)row * ldc + col] = f2bf(acc[i][j][r]);
        }
  } else if (MODE == 2) {
    ushort* C = (ushort*)Cg + (long)bz * sC;
    #pragma unroll
    for (int i = 0; i < 4; i++)
      #pragma unroll
      for (int j = 0; j < 4; j++)
        #pragma unroll
        for (int r = 0; r < 4; r++) {
          const int row = blockRow + wm + i * 16 + rq + r;
          const int col = blockCol + wn + j * 16 + cq;
          const float x = acc[i][j][r] + csum[(long)bz * N_ + row] * w0[col] + bexp[col];
          const float sp = fmaxf(x, 0.f) + log1pf(expf(-fabsf(x)));
          C[(long)row * ldc + colOff + col] = f2bf(sp);
        }
  } else {
    float* C = (float*)Cg + (long)bz * sC;
    #pragma unroll
    for (int i = 0; i < 4; i++)
      #pragma unroll
      for (int j = 0; j < 4; j++)
        #pragma unroll
        for (int r = 0; r < 4; r++) {
          const int row = blockRow + wm + i * 16 + rq + r;
          const int col = blockCol + wn + j * 16 + cq;
          C[(long)row * ldc + col] = acc[i][j][r];
        }
  }
}

// ---------------- launch ----------------
extern "C" void kernel_launch(void* const* d_in, const int* in_sizes, int n_in,
                              void* d_out, int out_size, void* d_ws, size_t ws_size,
                              hipStream_t stream) {
  const float* data    = (const float*)d_in[0];
  const float* W_exp   = (const float*)d_in[1];
  const float* b_exp   = (const float*)d_in[2];
  const float* W_merge = (const float*)d_in[3];

  char* ws = (char*)d_ws;
  const size_t MB = 1024 * 1024;
  ushort* cnv  = (ushort*)(ws);             // 32MB: cn, then reused as v_out
  ushort* sim  = (ushort*)(ws + 32 * MB);   // 32MB
  ushort* pe   = (ushort*)(ws + 64 * MB);   // 8MB
  ushort* weT  = (ushort*)(ws + 72 * MB);   // 8MB:  W_exp[1:,:]^T
  ushort* wmT  = (ushort*)(ws + 80 * MB);   // 16MB: W_merge^T
  ushort* catA = (ushort*)(ws + 96 * MB);   // 64MB: [data | counter] bf16
  float*  csum = (float*)(ws + 160 * MB);   // 128KB

  hipMemsetAsync(csum, 0, (size_t)B_ * N_ * sizeof(float), stream);
  prep_cn<<<B_ * N_, 256, 0, stream>>>(data, cnv, catA);
  prep_pe<<<(N_ * N_) / 256, 256, 0, stream>>>(pe);
  transpose_bf16<<<dim3(D_ / 32, D_ / 32), dim3(32, 8), 0, stream>>>(W_exp + D_, weT, D_, D_);
  transpose_bf16<<<dim3(D_ / 32, (2 * D_) / 32), dim3(32, 8), 0, stream>>>(W_merge, wmT, 2 * D_, D_);

  dim3 blk(256);
  // G1: sim = relu(cn cn^T) symmetric-triangular, csum row+col sums
  gemm_sym<<<dim3(136, 1, B_), blk, 0, stream>>>(cnv, sim, csum);
  dim3 g(N_ / BM, N_ / BN, B_);
  // G2: v_out = pe @ sim  (sim symmetric -> NT form), into cnv region (cn is dead)
  gemm_bt<1><<<g, blk, 0, stream>>>(pe, sim, cnv, N_, 0, (long)N_ * N_,
                                    (long)N_ * N_, N_, 0, nullptr, nullptr, nullptr);
  // G3: catA[:, D:] = softplus(v_out @ W_exp[1:] + csum*w0 + b_exp)
  gemm_bt<2><<<g, blk, 0, stream>>>(cnv, weT, catA, N_, (long)N_ * N_, 0,
                                    (long)N_ * 2 * D_, 2 * D_, D_, csum, W_exp, b_exp);
  // G4: out = catA @ W_merge
  gemm_bt<3><<<g, blk, 0, stream>>>(catA, wmT, d_out, 2 * D_, (long)N_ * 2 * D_, 0,
                                    (long)N_ * D_, D_, 0, nullptr, nullptr, nullptr);
}